// Round 4
// baseline (711.540 us; speedup 1.0000x reference)
//
#include <hip/hip_runtime.h>
#include <hip/hip_bf16.h>

#define B_ 16
#define S_ 8192
#define H_ 256
#define K_ 512           // 2H
#define NT32_ 8          // 256 cols / 32
#define NKS_ 32          // K / 16
#define NCHUNK_ 16       // 2 ks-slices per chunk

typedef __attribute__((ext_vector_type(8)))  short bf16x8;
typedef __attribute__((ext_vector_type(16))) float f32x16;
typedef unsigned int u32;

static __device__ __forceinline__ unsigned short f2bf(float x) {
    __hip_bfloat16 h = __float2bfloat16(x);
    unsigned short r;
    __builtin_memcpy(&r, &h, 2);
    return r;
}

static __device__ __forceinline__ bf16x8 pack8(float4 f0, float4 f1) {
    bf16x8 r;
    r[0] = (short)f2bf(f0.x); r[1] = (short)f2bf(f0.y);
    r[2] = (short)f2bf(f0.z); r[3] = (short)f2bf(f0.w);
    r[4] = (short)f2bf(f1.x); r[5] = (short)f2bf(f1.y);
    r[6] = (short)f2bf(f1.z); r[7] = (short)f2bf(f1.w);
    return r;
}

static __device__ __forceinline__ float fast_tanh(float x) {
    x = fminf(15.f, fmaxf(-15.f, x));
    float e = __expf(2.f * x);
    return 1.f - 2.f * __builtin_amdgcn_rcpf(e + 1.f);
}

static __device__ __forceinline__ void gload_lds16(const void* g, void* l) {
    __builtin_amdgcn_global_load_lds((const __attribute__((address_space(1))) u32*)g,
                                     (__attribute__((address_space(3))) u32*)l, 16, 0, 0);
}

// ---------------------------------------------------------------------------
// Fused prep:
//  blocks 0..15  : repack W2[k][n]=attn_w[n][256+k] (bf16) into 32x32x16 MFMA
//                  B-fragment order: slot = (ks*8+nt)*64+lane holds 8 bf16 of
//                  B[k = ks*16+(lane>>5)*8+j][n = nt*32+(lane&31)], j=0..7.
//  blocks 16..31 : q[b][h] = attn_b[h] + attn_w[h][0:256] . hidden[b]
// ---------------------------------------------------------------------------
__global__ __launch_bounds__(1024) void prep_kernel(const float* __restrict__ w,
                                                    const float* __restrict__ bias,
                                                    const float* __restrict__ hid,
                                                    bf16x8* __restrict__ wfrag,
                                                    float* __restrict__ q) {
    int blk = blockIdx.x;
    int tid = threadIdx.x;
    if (blk < 16) {
        int slot = blk * 1024 + tid;        // 0..16383
        int lane = slot & 63;
        int nt   = (slot >> 6) & 7;
        int ks   = slot >> 9;
        int n  = (nt << 5) + (lane & 31);
        int k0 = (ks << 4) + ((lane >> 5) << 3);
        const float* src = w + n * 768 + 256 + k0;
        float4 f0 = *(const float4*)(src);
        float4 f1 = *(const float4*)(src + 4);
        wfrag[slot] = pack8(f0, f1);
    } else {
        int b = blk - 16;
        int h = tid >> 2, part = tid & 3;
        const float* wr = w + h * 768 + part * 64;
        const float* hb = hid + b * H_ + part * 64;
        float acc = 0.f;
#pragma unroll
        for (int i = 0; i < 16; ++i) {
            float4 a = *(const float4*)(wr + i * 4);
            float4 x = *(const float4*)(hb + i * 4);
            acc += a.x * x.x + a.y * x.y + a.z * x.z + a.w * x.w;
        }
        acc += __shfl_xor(acc, 1);
        acc += __shfl_xor(acc, 2);
        if (part == 0) q[b * H_ + h] = acc + bias[h];
    }
}

// ---------------------------------------------------------------------------
// Energy v4: block = 128 rows x 256 cols, 4 waves, one 32-row m-band each.
// B staged through double-buffered 16 KB LDS chunks (2 ks-slices) via
// global_load_lds; A streamed from global with a depth-4 prefetch ring;
// __launch_bounds__(256,3) forces 3 blocks/CU (12 waves) for latency hiding.
// ---------------------------------------------------------------------------
__global__ __launch_bounds__(256, 3) void energy_kernel(const float* __restrict__ enc,
                                                        const char* __restrict__ wfrag,
                                                        const float* __restrict__ qv,
                                                        const float* __restrict__ vv,
                                                        float* __restrict__ ener) {
    __shared__ char Bs[2][16384];           // 32 KB double-buffered B chunks

    const int bid  = blockIdx.x;
    const int b    = bid >> 6;              // 64 s-tiles per batch
    const int s0   = (bid & 63) * 128;
    const int tid  = threadIdx.x;
    const int lane = tid & 63;
    const int wv   = tid >> 6;
    const int lc   = lane & 31;             // row-within-mtile / col-within-ntile
    const int hi   = lane >> 5;
    const int r0   = s0 + wv * 32;

    // A row pointer: row r0+lc, k-offset hi*8 (floats)
    const float* arow = enc + ((size_t)(b * S_ + r0 + lc)) * K_ + hi * 8;

    // ---- stage chunks 0 and 1 (16 KB each) ----
#pragma unroll
    for (int i = 0; i < 4; ++i) {
        int off = i * 4096 + tid * 16;
        gload_lds16(wfrag + off,         Bs[0] + off);
        gload_lds16(wfrag + 16384 + off, Bs[1] + off);
    }

    // ---- A prefetch prologue: ks = 0..3 ----
    float4 fbuf[4][2];
#pragma unroll
    for (int p = 0; p < 4; ++p) {
        fbuf[p][0] = *(const float4*)(arow + p * 16);
        fbuf[p][1] = *(const float4*)(arow + p * 16 + 4);
    }

    f32x16 acc[NT32_];
#pragma unroll
    for (int nt = 0; nt < NT32_; ++nt)
#pragma unroll
        for (int r = 0; r < 16; ++r) acc[nt][r] = 0.f;

    __syncthreads();                        // drains stages + A prologue

#pragma unroll
    for (int c = 0; c < NCHUNK_; ++c) {
        const char* Bb = Bs[c & 1];
#pragma unroll
        for (int ksl = 0; ksl < 2; ++ksl) {
            const int ks = c * 2 + ksl;
            bf16x8 a = pack8(fbuf[ks & 3][0], fbuf[ks & 3][1]);
            if (ks + 4 < NKS_) {            // refill ring slot
                fbuf[ks & 3][0] = *(const float4*)(arow + (ks + 4) * 16);
                fbuf[ks & 3][1] = *(const float4*)(arow + (ks + 4) * 16 + 4);
            }
#pragma unroll
            for (int nt = 0; nt < NT32_; ++nt) {
                bf16x8 bfr = *(const bf16x8*)(Bb + ksl * 8192 + nt * 1024 + lane * 16);
                acc[nt] = __builtin_amdgcn_mfma_f32_32x32x16_bf16(a, bfr, acc[nt], 0, 0, 0);
            }
        }
        __syncthreads();                    // all waves done with Bs[c&1]
        if (c < NCHUNK_ - 2) {              // stage chunk c+2 into freed buffer
            const char* src = wfrag + (c + 2) * 16384;
#pragma unroll
            for (int i = 0; i < 4; ++i) {
                int off = i * 4096 + tid * 16;
                gload_lds16(src + off, Bs[c & 1] + off);
            }
        }
    }

    // ---- epilogue: e[row] = sum_h v[h] * tanh(q[h] + acc) ----
    const float* qb = qv + b * H_;
    float er[16];
#pragma unroll
    for (int r = 0; r < 16; ++r) er[r] = 0.f;
#pragma unroll
    for (int nt = 0; nt < NT32_; ++nt) {
        float qn = qb[nt * 32 + lc];
        float vn = vv[nt * 32 + lc];
#pragma unroll
        for (int r = 0; r < 16; ++r)
            er[r] += vn * fast_tanh(qn + acc[nt][r]);
    }
#pragma unroll
    for (int r = 0; r < 16; ++r) {
        er[r] += __shfl_xor(er[r], 1);
        er[r] += __shfl_xor(er[r], 2);
        er[r] += __shfl_xor(er[r], 4);
        er[r] += __shfl_xor(er[r], 8);
        er[r] += __shfl_xor(er[r], 16);
    }
    if (lc == 0) {
        float* op = ener + b * S_ + r0;
#pragma unroll
        for (int r = 0; r < 16; ++r)
            op[(r & 3) + 8 * (r >> 2) + 4 * hi] = er[r];
    }
}

// ---------------------------------------------------------------------------
// Softmax over S per batch
// ---------------------------------------------------------------------------
__global__ __launch_bounds__(1024) void softmax_kernel(const float* __restrict__ ener,
                                                       float* __restrict__ out) {
    __shared__ float redm[16], reds[16];
    int b = blockIdx.x, tid = threadIdx.x;
    int lane = tid & 63, wv = tid >> 6;
    const float* e = ener + b * S_;
    float v[8];
#pragma unroll
    for (int i = 0; i < 8; ++i) v[i] = e[i * 1024 + tid];
    float m = v[0];
#pragma unroll
    for (int i = 1; i < 8; ++i) m = fmaxf(m, v[i]);
#pragma unroll
    for (int msk = 1; msk < 64; msk <<= 1) m = fmaxf(m, __shfl_xor(m, msk));
    if (lane == 0) redm[wv] = m;
    __syncthreads();
    float M = redm[0];
#pragma unroll
    for (int i = 1; i < 16; ++i) M = fmaxf(M, redm[i]);
    float s = 0.f;
#pragma unroll
    for (int i = 0; i < 8; ++i) { v[i] = __expf(v[i] - M); s += v[i]; }
#pragma unroll
    for (int msk = 1; msk < 64; msk <<= 1) s += __shfl_xor(s, msk);
    if (lane == 0) reds[wv] = s;
    __syncthreads();
    float T = 0.f;
#pragma unroll
    for (int i = 0; i < 16; ++i) T += reds[i];
    float inv = 1.0f / T;
    float* ob = out + b * S_;
#pragma unroll
    for (int i = 0; i < 8; ++i) ob[i * 1024 + tid] = v[i] * inv;
}

extern "C" void kernel_launch(void* const* d_in, const int* in_sizes, int n_in,
                              void* d_out, int out_size, void* d_ws, size_t ws_size,
                              hipStream_t stream) {
    const float* hidden = (const float*)d_in[0];
    const float* enc    = (const float*)d_in[1];
    const float* attn_w = (const float*)d_in[2];
    const float* attn_b = (const float*)d_in[3];
    const float* v      = (const float*)d_in[4];
    float* out = (float*)d_out;

    char* ws = (char*)d_ws;
    bf16x8* wfrag = (bf16x8*)ws;                          // 256 KB
    float*  q     = (float*)(ws + 262144);                // 16 KB
    float*  ener  = (float*)(ws + 262144 + 16384);        // 512 KB

    prep_kernel<<<32, 1024, 0, stream>>>(attn_w, attn_b, hidden, wfrag, q);
    energy_kernel<<<B_ * (S_ / 128), 256, 0, stream>>>(enc, (const char*)wfrag, q, v, ener);
    softmax_kernel<<<B_, 1024, 0, stream>>>(ener, out);
}